// Round 14
// baseline (423.247 us; speedup 1.0000x reference)
//
#include <hip/hip_runtime.h>
#include <hip/hip_bf16.h>

// GCN: 2x GCNConv(128->128) + LeakyReLU(0.1) + mean over channels.
// N=50000, E=1600000, D=128, fp32 in/out.
//
// R14: mega-fused build kernel. Evidence: R7-R13 "non-gather" time is a
//     stubborn ~140us while kernel-body estimates sum to ~60 -> serialized
//     build dispatches (hist->scan->scatter->sort) + ramps/tails/gaps.
//     Fix: ONE kernel; blocks [0,CHN) run the build chain with in-kernel
//     ticket barriers (K2's proven atomic+threadfence pattern; threadfence
//     emits L2 wb/inv for cross-XCD visibility); blocks [CHN,CHN+782) run
//     the MFMA gemm CONCURRENTLY (independent: g is unscaled bf16(x@W1));
//     trailing 33 blocks do w2m. Deadlock-safe: LDS 34.8KB -> 4 blocks/CU
//     -> 1024 co-resident slots >> 391 build blocks (dispatched first).
//     Gather: R12 full-row (56us, known-good; quartered retired after R8/
//     R11/R13 all hit the 22MB FETCH floor but lost on exec overhead).
// Math (verified R2-R13): h[u]=bf16((x@W1)[u]);
//   mg[u]=dinv[u]*dot(lrelu(dinv[u]*sum_{n in N(u)+u} dinv[n]*h[n] + b1), mean_j W2[:,j]);
//   out[v]=dinv[v]*(mg[v]+sum mg[nbr]) + mean(b2).

#define N_NODES 50000
#define NPAD 50048
#define D 128
#define BK 196           // node buckets: v>>8
#define CHUNK 4096       // edges per build-chunk block

// ticket slots (in d_ws, zeroed by hipMemsetAsync before launch)
#define TICK_H 0         // hist arrivals        (target CHN)
#define TICK_S 1         // scan arrivals        (target BK)
#define TICK_B 2         // B[] ready flag       (target 1)
#define TICK_X 3         // scatter arrivals     (target CHN)

typedef unsigned int uint;
typedef unsigned short u16;
typedef __attribute__((ext_vector_type(8))) short short8;   // 8 bf16 (4 VGPRs)
typedef __attribute__((ext_vector_type(4))) float floatx4;

__device__ __forceinline__ u16 cvt_bf16(float f) {
    uint u = __float_as_uint(f);
    return (u16)((u + 0x7fffu + ((u >> 16) & 1u)) >> 16);   // RNE
}
__device__ __forceinline__ uint pack_bf2(float a, float b) {
    return (uint)cvt_bf16(a) | ((uint)cvt_bf16(b) << 16);
}

// block-wide arrive: all stores drained + released, then one atomic bump
__device__ __forceinline__ void bar_arrive(uint* flag) {
    __syncthreads();
    __threadfence();                       // release (L2 writeback on gfx9)
    if (threadIdx.x == 0) atomicAdd(flag, 1u);
}
// block-wide wait: one lane spins, then acquire fence for normal loads
__device__ __forceinline__ void bar_wait(uint* flag, uint target) {
    if (threadIdx.x == 0) {
        while (atomicAdd(flag, 0u) < target) __builtin_amdgcn_s_sleep(2);
    }
    __syncthreads();
    __threadfence();                       // acquire (L2 invalidate)
}

#define WT_STRIDE 136
union BuildSmem {
    uint h[256];                           // hist counters (BK used)
    uint s[256];                           // scan workspace
    uint cur[256];                         // scatter cursors (BK used)
    struct { uint cnt[256], s[256], cur[256]; } sort;
    u16 wt[128 * WT_STRIDE];               // 34.8 KB (gemm W1^T)
};

// ---------------- K1: fused build chain || MFMA gemm || w2m ----------------
__global__ __launch_bounds__(256) void build_kernel(
    const int* __restrict__ src, const int* __restrict__ dst,
    const float* __restrict__ A, const float* __restrict__ W,
    const float* __restrict__ W2, const float* __restrict__ b2,
    uint* __restrict__ H, uint* __restrict__ T, uint* __restrict__ B,
    int* __restrict__ row, float* __restrict__ dinv, u16* __restrict__ esrc,
    uint* __restrict__ EB, uint* __restrict__ G32, float* __restrict__ w2m,
    uint* __restrict__ tick, int E, int N, int CHN) {
    __shared__ BuildSmem sm;
    __shared__ uint tk_sh;
    int t = threadIdx.x;
    int b = blockIdx.x;

    if (b < CHN) {
        // ======== phase H: histogram chunk b ========
        if (t < BK) sm.h[t] = 0;
        __syncthreads();
        {
            int e0 = b * CHUNK;
            for (int i = t; i < CHUNK; i += 256) {
                int e = e0 + i;
                if (e < E) atomicAdd(&sm.h[dst[e] >> 8], 1u);
            }
        }
        __syncthreads();
        if (t < BK) H[t * CHN + b] = sm.h[t];
        bar_arrive(&tick[TICK_H]);

        // ======== phase S: per-bucket scan (blocks < BK) ========
        if (b < BK) {
            bar_wait(&tick[TICK_H], (uint)CHN);
            uint carry = 0;
            for (int base = 0; base < CHN; base += 256) {
                int idx = base + t;
                uint v = (idx < CHN) ? H[b * CHN + idx] : 0u;
                sm.s[t] = v;
                __syncthreads();
#pragma unroll
                for (int off = 1; off < 256; off <<= 1) {
                    uint u = (t >= off) ? sm.s[t - off] : 0u;
                    __syncthreads();
                    sm.s[t] += u;
                    __syncthreads();
                }
                if (idx < CHN) H[b * CHN + idx] = carry + sm.s[t] - v;
                carry += sm.s[255];
                __syncthreads();
            }
            if (t == 0) atomicExch(&T[b], carry);   // device-scope (coherent)
            __syncthreads();
            __threadfence();                        // release scanned H
            if (t == 0) tk_sh = atomicAdd(&tick[TICK_S], 1u);
            __syncthreads();
            if (tk_sh == BK - 1) {                  // last scan block: totals
                __threadfence();                    // acquire T
                uint v = (t < BK) ? atomicAdd(&T[t], 0u) : 0u;
                sm.s[t] = v;
                __syncthreads();
#pragma unroll
                for (int off = 1; off < 256; off <<= 1) {
                    uint u = (t >= off) ? sm.s[t - off] : 0u;
                    __syncthreads();
                    sm.s[t] += u;
                    __syncthreads();
                }
                if (t < BK) B[t] = sm.s[t] - v;
                if (t == 0) { B[BK] = (uint)E; row[N] = E; }
                __syncthreads();
                __threadfence();                    // release B
                if (t == 0) atomicExch(&tick[TICK_B], 1u);
            }
        }

        // ======== phase X: scatter chunk b ========
        bar_wait(&tick[TICK_B], 1u);                // implies all scans done
        if (t < BK) sm.cur[t] = B[t] + H[t * CHN + b];
        __syncthreads();
        {
            int e0 = b * CHUNK;
            for (int i = t; i < CHUNK; i += 256) {
                int e = e0 + i;
                if (e < E) {
                    int d = dst[e];
                    uint slot = atomicAdd(&sm.cur[d >> 8], 1u);
                    EB[slot] = ((uint)(d & 255) << 16) | (uint)src[e];
                }
            }
        }
        bar_arrive(&tick[TICK_X]);

        // ======== phase B: bucket sort (blocks < BK) ========
        if (b < BK) {
            bar_wait(&tick[TICK_X], (uint)CHN);
            uint base = B[b], ne = B[b + 1] - base;
            sm.sort.cnt[t] = 0;
            __syncthreads();
            for (uint i = t; i < ne; i += 256) atomicAdd(&sm.sort.cnt[EB[base + i] >> 16], 1u);
            __syncthreads();
            uint c = sm.sort.cnt[t];
            sm.sort.s[t] = c;
            __syncthreads();
#pragma unroll
            for (int off = 1; off < 256; off <<= 1) {
                uint u = (t >= off) ? sm.sort.s[t - off] : 0u;
                __syncthreads();
                sm.sort.s[t] += u;
                __syncthreads();
            }
            uint p = sm.sort.s[t] - c;
            int v = (b << 8) + t;
            if (v < N) {
                row[v] = (int)(base + p);
                dinv[v] = rsqrtf((float)(c + 1u));  // +1 self-loop
            }
            sm.sort.cur[t] = base + p;
            __syncthreads();
            for (uint i = t; i < ne; i += 256) {
                uint u = EB[base + i];
                uint slot = atomicAdd(&sm.sort.cur[u >> 16], 1u);
                esrc[slot] = (u16)(u & 0xffffu);
            }
        }
    } else if (b < CHN + (N + 63) / 64) {
        // ======== MFMA gemm: g16[M,128] = bf16( x @ W1 ), row-major ========
        int bid = b - CHN;
        int M = N;
        for (int i = t; i < 128 * 128; i += 256) {   // stage W1^T as bf16
            int k = i >> 7, n = i & 127;
            sm.wt[n * WT_STRIDE + k] = cvt_bf16(W[i]);
        }
        __syncthreads();

        int wave = t >> 6, lane = t & 63;
        int m = lane & 15, quad = lane >> 4;
        int rowa = bid * 64 + wave * 16 + m;
        int rowc = rowa < M ? rowa : M - 1;
        const float* Arow = A + (long)rowc * D;

        short8 afrag[4];
#pragma unroll
        for (int kt = 0; kt < 4; kt++) {
            int k0 = kt * 32 + quad * 8;
            float4 f0 = *(const float4*)(Arow + k0);
            float4 f1 = *(const float4*)(Arow + k0 + 4);
            short8 af;
            af[0] = (short)cvt_bf16(f0.x); af[1] = (short)cvt_bf16(f0.y);
            af[2] = (short)cvt_bf16(f0.z); af[3] = (short)cvt_bf16(f0.w);
            af[4] = (short)cvt_bf16(f1.x); af[5] = (short)cvt_bf16(f1.y);
            af[6] = (short)cvt_bf16(f1.z); af[7] = (short)cvt_bf16(f1.w);
            afrag[kt] = af;
        }

        int orow0 = bid * 64 + wave * 16;
        for (int n0 = 0; n0 < 128; n0 += 16) {
            floatx4 acc = {0.f, 0.f, 0.f, 0.f};
#pragma unroll
            for (int kt = 0; kt < 4; kt++) {
                short8 bf = *(const short8*)(sm.wt + (n0 + m) * WT_STRIDE + kt * 32 + quad * 8);
                acc = __builtin_amdgcn_mfma_f32_16x16x32_bf16(afrag[kt], bf, acc, 0, 0, 0);
            }
#pragma unroll
            for (int r = 0; r < 4; r++) {
                float val = acc[r];
                float oth = __shfl_xor(val, 1, 64);      // partner column
                int orow = orow0 + quad * 4 + r;
                if (orow < M && (m & 1) == 0)
                    G32[(long)orow * 64 + ((n0 + m) >> 1)] = pack_bf2(val, oth);
            }
        }
    } else {
        // ======== w2m waves: one wave per output k ========
        int wave = t >> 6, lane = t & 63;
        int k = (b - CHN - (N + 63) / 64) * 4 + wave;    // 33 blocks x 4 = 132 >= 129
        if (k < 128) {
            float s = W2[k * 128 + lane] + W2[k * 128 + 64 + lane];
#pragma unroll
            for (int off = 32; off > 0; off >>= 1) s += __shfl_down(s, off, 64);
            if (lane == 0) w2m[k] = s * (1.0f / 128.0f);
        } else if (k == 128) {
            float s = b2[lane] + b2[lane + 64];
#pragma unroll
            for (int off = 32; off > 0; off >>= 1) s += __shfl_down(s, off, 64);
            if (lane == 0) w2m[128] = s * (1.0f / 128.0f);
        }
    }
}

// ---------------- K2: fused gather(bf16, dinv-fma) + leakyrelu + dot(w2m) ----------------
// R12 version (known 56us): one wave/node; 8 chains x 8 lanes; 2 uint4/edge.
__global__ __launch_bounds__(256) void gather_node_kernel(
    const int* __restrict__ row, const u16* __restrict__ esrc,
    const uint* __restrict__ g16, const float* __restrict__ dinv,
    const float* __restrict__ b1, const float* __restrict__ w2m,
    float* __restrict__ mg, int N) {
    int wave = threadIdx.x >> 6;
    int lane = threadIdx.x & 63;
    int sub = lane & 7;        // 16-channel slice: uint4 pair 2*sub, 2*sub+1
    int nb = lane >> 3;        // 8 neighbor chains
    int v = blockIdx.x * 4 + wave;
    if (v >= N) return;

    const uint4* gv = (const uint4*)g16;   // 16 uint4 per 256B row
    float dvv = dinv[v];
    float acc[16];
#pragma unroll
    for (int i = 0; i < 16; i++) acc[i] = 0.f;

#define ACC8(ua, ub, wgt) {                                              \
    uint uu[8] = {(ua).x, (ua).y, (ua).z, (ua).w, (ub).x, (ub).y, (ub).z, (ub).w}; \
    _Pragma("unroll")                                                    \
    for (int i = 0; i < 8; i++) {                                        \
        acc[2*i]   += (wgt) * __uint_as_float(uu[i] << 16);              \
        acc[2*i+1] += (wgt) * __uint_as_float(uu[i] & 0xffff0000u);      \
    } }

    if (nb == 0) {             // self-loop term: dinv[v]*h[v]
        long rb = (long)v * 16 + 2 * sub;
        uint4 ua = gv[rb], ub = gv[rb + 1];
        ACC8(ua, ub, dvv)
    }
    int jb = row[v], je = row[v + 1];
    int j = jb + nb;
    if (j < je) {              // 2-deep pipeline per chain
        int s0 = esrc[j];
        float wA = dinv[s0];
        long r0 = (long)s0 * 16 + 2 * sub;
        uint4 p0 = gv[r0], p1 = gv[r0 + 1];
        j += 8;
        while (j < je) {
            int s1 = esrc[j];
            float wB = dinv[s1];
            long r1 = (long)s1 * 16 + 2 * sub;
            uint4 q0 = gv[r1], q1 = gv[r1 + 1];
            j += 8;
            ACC8(p0, p1, wA)
            p0 = q0; p1 = q1; wA = wB;
        }
        ACC8(p0, p1, wA)
    }
#undef ACC8

    // reduce the 8 chains
#pragma unroll
    for (int i = 0; i < 16; i++) {
        acc[i] += __shfl_xor(acc[i], 8, 64);
        acc[i] += __shfl_xor(acc[i], 16, 64);
        acc[i] += __shfl_xor(acc[i], 32, 64);
    }

    if (nb == 0) {             // lane sub holds channels 16*sub .. 16*sub+15
        const float4* bp = (const float4*)b1;
        const float4* wp = (const float4*)w2m;
        float s = 0.f;
#pragma unroll
        for (int q4 = 0; q4 < 4; q4++) {
            float4 bb = bp[sub * 4 + q4];
            float4 wm = wp[sub * 4 + q4];
            float t0 = dvv * acc[4*q4 + 0] + bb.x; t0 = t0 >= 0.f ? t0 : 0.1f * t0;
            float t1 = dvv * acc[4*q4 + 1] + bb.y; t1 = t1 >= 0.f ? t1 : 0.1f * t1;
            float t2 = dvv * acc[4*q4 + 2] + bb.z; t2 = t2 >= 0.f ? t2 : 0.1f * t2;
            float t3 = dvv * acc[4*q4 + 3] + bb.w; t3 = t3 >= 0.f ? t3 : 0.1f * t3;
            s += t0 * wm.x + t1 * wm.y + t2 * wm.z + t3 * wm.w;
        }
        s += __shfl_xor(s, 1, 64);
        s += __shfl_xor(s, 2, 64);
        s += __shfl_xor(s, 4, 64);
        if (sub == 0) mg[v] = dvv * s;
    }
}

// ---------------- K3: scalar aggregate for conv2 + mean ----------------
__global__ void out_kernel(const int* __restrict__ row, const u16* __restrict__ esrc,
                           const float* __restrict__ mg, const float* __restrict__ dinv,
                           const float* __restrict__ w2m, float* __restrict__ out, int N) {
    int v = blockIdx.x * blockDim.x + threadIdx.x;
    if (v >= N) return;
    float acc = mg[v];
    int jb = row[v], je = row[v + 1];
    int j = jb;
    for (; j + 8 <= je; j += 8) {
        acc += mg[esrc[j]] + mg[esrc[j + 1]] + mg[esrc[j + 2]] + mg[esrc[j + 3]] +
               mg[esrc[j + 4]] + mg[esrc[j + 5]] + mg[esrc[j + 6]] + mg[esrc[j + 7]];
    }
    for (; j < je; j++) acc += mg[esrc[j]];
    out[v] = dinv[v] * acc + w2m[128];
}

extern "C" void kernel_launch(void* const* d_in, const int* in_sizes, int n_in,
                              void* d_out, int out_size, void* d_ws, size_t ws_size,
                              hipStream_t stream) {
    const float* x  = (const float*)d_in[0];
    const int* ei   = (const int*)d_in[1];
    const float* W1 = (const float*)d_in[2];
    const float* b1 = (const float*)d_in[3];
    const float* W2 = (const float*)d_in[4];
    const float* b2 = (const float*)d_in[5];
    float* out = (float*)d_out;

    const int N = N_NODES;
    const int E = in_sizes[1] / 2;
    const int* src = ei;
    const int* dst = ei + E;
    const int CHN = (E + CHUNK - 1) / CHUNK;   // 391
    const int nblocks = (N + 255) / 256;       // 196

    // workspace (4B units); tick first (zeroed by async memset)
    uint*     tick    = (uint*)d_ws;                      // [16]
    float*    dinv    = (float*)(tick + 16);              // [NPAD]
    int*      row     = (int*)(dinv + NPAD);              // [NPAD+16]
    uint*     B       = (uint*)(row + NPAD + 16);         // [256] (BK+1 used)
    float*    w2m     = (float*)(B + 256);                // [256] ([128]=mean b2)
    float*    mg      = w2m + 256;                        // [NPAD]
    uint*     T       = (uint*)(mg + NPAD);               // [256]
    uint*     g16u    = T + 256;                          // [NPAD*64] (16B aligned)
    u16*      esrc    = (u16*)(g16u + (long)NPAD * 64);   // [E] u16
    uint*     H       = (uint*)(esrc + E);                // [BK*CHN]
    uint*     EB      = H + BK * CHN;                     // [E]

    // zero the ticket block (everything else initialized in-kernel)
    hipMemsetAsync(tick, 0, 64, stream);

    // K1: build chain (CHN blocks, ticket barriers) || gemm (782) || w2m (33)
    const int gemm_blocks = (N + 63) / 64;     // 782
    build_kernel<<<CHN + gemm_blocks + 33, 256, 0, stream>>>(
        src, dst, x, W1, W2, b2, H, T, B, row, dinv, esrc, EB, g16u, w2m,
        tick, E, N, CHN);

    // K2: gather + lrelu + dot -> mg
    gather_node_kernel<<<(N + 3) / 4, 256, 0, stream>>>(row, esrc, g16u, dinv, b1, w2m, mg, N);

    // K3: scalar aggregate + mean -> out
    out_kernel<<<nblocks, 256, 0, stream>>>(row, esrc, mg, dinv, w2m, out, N);
}